// Round 6
// baseline (196.450 us; speedup 1.0000x reference)
//
#include <hip/hip_runtime.h>
#include <hip/hip_bf16.h>
#include <stdint.h>

typedef _Float16 f16_t;
typedef f16_t f16x8 __attribute__((ext_vector_type(8)));
typedef f16_t f16x2 __attribute__((ext_vector_type(2)));
typedef float f32x4 __attribute__((ext_vector_type(4)));

__device__ inline f16x2 as_f16x2(int v) {
    union { int i; f16x2 h; } u; u.i = v; return u.h;
}

// CK-style lgkm-only barrier: LDS producer/consumer sync WITHOUT draining
// in-flight global loads (prefetches survive across iterations).
#define LGKM_BARRIER() asm volatile("s_waitcnt lgkmcnt(0)\n\ts_barrier" ::: "memory")

// ---------------------------------------------------------------------------
// Kernel 1 (merged prep):
//  blocks 0..511  : transpose+cast x(B,C,H,W) f32 -> xt(B,H,W,C) f16.
//    LDS layout: elem (x,c) at x*256 + ((c>>3 ^ (x&31))<<3) + (c&7)
//    (chunk-XOR swizzle: scalar writes land ~2-way, b128 reads aligned).
//  blocks 512..575: pack weight (O,C,3,3) f32 -> Wp f16 A-fragment layout
//    Wp[((kb2*2+s)*256 + o)*32 + quad*8 + e], c = cp*64 + s*32 + quad*8 + e.
// ---------------------------------------------------------------------------
__global__ __launch_bounds__(256) void k_prep(const float* __restrict__ x,
                                              const float* __restrict__ w,
                                              f16_t* __restrict__ xt,
                                              f16_t* __restrict__ Wp) {
    __shared__ __align__(16) char smem[36864];
    const int t = threadIdx.x;
    if (blockIdx.x < 512) {
        f16_t* tT = (f16_t*)smem;                 // 64 x 256, swizzled, 32 KB
        const int b = blockIdx.x >> 6;
        const int y = blockIdx.x & 63;
        const float* src = x + ((size_t)(b * 256) * 64 + y) * 64;
        const int x4 = (t & 15) * 4;
        const int cs = t >> 4;
#pragma unroll
        for (int cc = 0; cc < 256; cc += 16) {
            const int c = cc + cs;
            float4 v = *(const float4*)(src + (size_t)c * 4096 + x4);
            const int chunk = c >> 3, e = c & 7;
#pragma unroll
            for (int j = 0; j < 4; ++j) {
                const int xx = x4 + j;
                const float f = (j == 0) ? v.x : (j == 1) ? v.y : (j == 2) ? v.z : v.w;
                tT[xx * 256 + ((chunk ^ (xx & 31)) << 3) + e] = (f16_t)f;
            }
        }
        __syncthreads();
        f16_t* dst = xt + ((size_t)(b * 64 + y) * 64) * 256;
#pragma unroll
        for (int i = 0; i < 8; ++i) {
            const int s = t + 256 * i;
            const int xx = s >> 5, cg = s & 31;
            *(f16x8*)(dst + xx * 256 + cg * 8) =
                *(const f16x8*)(tT + xx * 256 + ((cg ^ (xx & 31)) << 3));
        }
    } else {
        float* lw = (float*)smem;                 // 4*2304 f32 = 36864 B
        const int o0 = (blockIdx.x - 512) * 4;
        const float4* src = (const float4*)(w + (size_t)o0 * 2304);
#pragma unroll
        for (int i = 0; i < 9; ++i)
            ((float4*)lw)[t + 256 * i] = src[t + 256 * i];
        __syncthreads();
#pragma unroll
        for (int i = 0; i < 5; ++i) {
            const int u = t + 256 * i;            // 0..1151
            if (u < 1152) {
                const int o = u / 288, r = u - o * 288;
                const int kb2 = r >> 3, rr = r & 7;
                const int s = rr >> 2, qq = rr & 3;
                const int kk = kb2 >> 2, cp = kb2 & 3;
                f16x8 v;
#pragma unroll
                for (int e = 0; e < 8; ++e) {
                    const int c = cp * 64 + s * 32 + qq * 8 + e;
                    v[e] = (f16_t)lw[o * 2304 + c * 9 + kk];
                }
                *(f16x8*)(Wp + ((size_t)(kb2 * 2 + s) * 256 + o0 + o) * 32 + qq * 8) = v;
            }
        }
    }
}

// ---------------------------------------------------------------------------
// Kernel 2: fused deformable-sample + GEMM, f16, depth-2 gather pipeline.
// Grid 512: b = blk&7 (XCD pin), h = blk>>3; 512 threads, 2 blocks/CU.
// Per iter: gather(it+2) issue | loadA(it+1) issue | MFMA(it) | combine(it+1)
// | lgkm-only barrier (global loads stay in flight across it).
// ---------------------------------------------------------------------------
__global__ __launch_bounds__(512, 4) void k_dcn(
    const f16_t* __restrict__ xt, const f16_t* __restrict__ Wp,
    const float* __restrict__ coff, const float* __restrict__ cwm,
    const float* __restrict__ bias, float* __restrict__ out) {

    __shared__ __align__(16) f16_t sS[2][64 * 64];   // 2 x 8 KB
    __shared__ __align__(16) int2 sT[9 * 64 * 4];    // [kk][px][corner] 18 KB

    const int blk = blockIdx.x;
    const int b  = blk & 7;
    const int h  = blk >> 3;
    const int t = threadIdx.x;
    const int wv = t >> 6;
    const int lane = t & 63;

    const int p = t >> 3;          // pixel (8 threads/pixel)
    const int q = t & 7;           // 8-channel slice

    const int fr = lane & 15;
    const int quad = lane >> 4;
    const int swz = fr & 7;

    // ---- precompute corner table for all 9 taps ----
    for (int u = t; u < 576; u += 512) {
        const int kk = u >> 6, wpx = u & 63;
        float oy = coff[((size_t)(b * 18 + kk * 2 + 0) * 64 + h) * 64 + wpx];
        float ox = coff[((size_t)(b * 18 + kk * 2 + 1) * 64 + h) * 64 + wpx];
        float m  = cwm [((size_t)(b * 9 + kk) * 64 + h) * 64 + wpx];
        float py = (float)(h - 1 + (kk / 3)) + oy;
        float px = (float)(wpx - 1 + (kk % 3)) + ox;
        float fy = floorf(py), fx = floorf(px);
        int y0 = (int)fy, x0 = (int)fx;
        int y1 = y0 + 1,  x1 = x0 + 1;
        float wy1 = py - fy, wx1 = px - fx;
        float wy0 = 1.0f - wy1, wx0 = 1.0f - wx1;
        bool vy0 = (y0 >= 0) && (y0 < 64), vy1 = (y1 >= 0) && (y1 < 64);
        bool vx0 = (x0 >= 0) && (x0 < 64), vx1 = (x1 >= 0) && (x1 < 64);
        int yc0 = min(max(y0, 0), 63), yc1 = min(max(y1, 0), 63);
        int xc0 = min(max(x0, 0), 63), xc1 = min(max(x1, 0), 63);
        const int base = b * 4096;
        float cw[4];
        int   ca[4];
        cw[0] = (vy0 && vx0) ? wy0 * wx0 * m : 0.0f;
        cw[1] = (vy0 && vx1) ? wy0 * wx1 * m : 0.0f;
        cw[2] = (vy1 && vx0) ? wy1 * wx0 * m : 0.0f;
        cw[3] = (vy1 && vx1) ? wy1 * wx1 * m : 0.0f;
        ca[0] = (base + yc0 * 64 + xc0) * 512;   // byte offsets (f16)
        ca[1] = (base + yc0 * 64 + xc1) * 512;
        ca[2] = (base + yc1 * 64 + xc0) * 512;
        ca[3] = (base + yc1 * 64 + xc1) * 512;
#pragma unroll
        for (int c = 0; c < 4; ++c) {
            union { unsigned short us; f16_t hh; } cv;
            cv.hh = (f16_t)cw[c];
            int wp = (int)cv.us | ((int)cv.us << 16);
            sT[(kk * 64 + wpx) * 4 + c] = make_int2(ca[c], wp);
        }
    }
    __syncthreads();

    // A-frag global base (elems): + it*16384 + s*8192 + mt*512
    const f16_t* wA = Wp + (wv * 32 + fr) * 32 + quad * 8;
    f16_t* const swb0 = &sS[0][p * 64 + ((q ^ (p & 7)) * 8)];
    const int qb = q * 16;                       // byte offset of ch slice

    f32x4 acc[2][4] = {};
    f16x8 aR[2][2][2];     // [parity][mt][s]
    f16x8 gR[2][4];        // [parity][corner] in-flight gathers
    int   wPk[2][4];       // packed f16x2 corner weights per parity

    // gathers for iter `it` -> gR[it&1], weights -> wPk[it&1]
    auto gather = [&](int it) {
        const int par = it & 1;
        const int kk = it >> 2, cp = it & 3;
        const int4* tp = (const int4*)&sT[(kk * 64 + p) * 4];
        int4 t0 = tp[0], t1 = tp[1];             // 2x ds_read_b128
        const int cb = cp * 128 + qb;
        const char* xb = (const char*)xt;
        gR[par][0] = *(const f16x8*)(xb + (t0.x + cb));
        gR[par][1] = *(const f16x8*)(xb + (t0.z + cb));
        gR[par][2] = *(const f16x8*)(xb + (t1.x + cb));
        gR[par][3] = *(const f16x8*)(xb + (t1.z + cb));
        wPk[par][0] = t0.y; wPk[par][1] = t0.w;
        wPk[par][2] = t1.y; wPk[par][3] = t1.w;
    };

    auto loadA = [&](int it) {
        const int par = it & 1;
        const f16_t* wn = wA + (size_t)it * 16384;
        aR[par][0][0] = *(const f16x8*)(wn);
        aR[par][0][1] = *(const f16x8*)(wn + 8192);
        aR[par][1][0] = *(const f16x8*)(wn + 512);
        aR[par][1][1] = *(const f16x8*)(wn + 8192 + 512);
    };

    // combine gathers for iter `it` and write its sS buffer
    auto combine = [&](int it) {
        const int par = it & 1;
        f16x2 w0 = as_f16x2(wPk[par][0]), w1 = as_f16x2(wPk[par][1]);
        f16x2 w2 = as_f16x2(wPk[par][2]), w3 = as_f16x2(wPk[par][3]);
        const f16x2* g0p = (const f16x2*)&gR[par][0];
        const f16x2* g1p = (const f16x2*)&gR[par][1];
        const f16x2* g2p = (const f16x2*)&gR[par][2];
        const f16x2* g3p = (const f16x2*)&gR[par][3];
        f16x8 ov; f16x2* op = (f16x2*)&ov;
#pragma unroll
        for (int j = 0; j < 4; ++j)
            op[j] = g0p[j] * w0 + g1p[j] * w1 + g2p[j] * w2 + g3p[j] * w3;
        *(f16x8*)(swb0 + par * 4096) = ov;
    };

    auto do_mfma = [&](int it) {
        const int par = it & 1;
        const f16_t* sb = &sS[par][0];
#pragma unroll
        for (int s = 0; s < 2; ++s) {
            const int coffe = ((s * 4 + quad) ^ swz) * 8;
            f16x8 bb[4];
#pragma unroll
            for (int nt = 0; nt < 4; ++nt)
                bb[nt] = *(const f16x8*)(sb + (nt * 16 + fr) * 64 + coffe);
#pragma unroll
            for (int mt = 0; mt < 2; ++mt)
#pragma unroll
                for (int nt = 0; nt < 4; ++nt)
                    acc[mt][nt] = __builtin_amdgcn_mfma_f32_16x16x32_f16(
                        aR[par][mt][s], bb[nt], acc[mt][nt], 0, 0, 0);
        }
    };

    // ---- prologue: fill depth-2 pipeline ----
    gather(0);
    gather(1);
    loadA(0);
    combine(0);                 // waits gR[0] only; gR[1], aR[0] stay in flight
    LGKM_BARRIER();             // sS[0] visible; vmem NOT drained

    // ---- main loop ----
#pragma unroll 2
    for (int it = 0; it < 36; ++it) {
        if (it + 2 < 36) gather(it + 2);     // into gR[it&1] (just consumed)
        if (it + 1 < 36) loadA(it + 1);
        do_mfma(it);                         // A: aR[it&1], B: sS[it&1]
        if (it + 1 < 36) combine(it + 1);    // gR[(it+1)&1] -> sS[(it+1)&1]
        LGKM_BARRIER();
    }

    // ---- epilogue: D layout col=lane&15 (px), row=(lane>>4)*4+r (O) ----
    const int rowq = quad * 4;
#pragma unroll
    for (int mt = 0; mt < 2; ++mt) {
#pragma unroll
        for (int r = 0; r < 4; ++r) {
            const int og = wv * 32 + mt * 16 + rowq + r;
            const float bs = bias[og];
            float* opn = out + ((size_t)(b * 256 + og) * 64 + h) * 64;
#pragma unroll
            for (int nt = 0; nt < 4; ++nt) {
                opn[nt * 16 + fr] = acc[mt][nt][r] + bs;
            }
        }
    }
}

// ---------------------------------------------------------------------------
extern "C" void kernel_launch(void* const* d_in, const int* in_sizes, int n_in,
                              void* d_out, int out_size, void* d_ws, size_t ws_size,
                              hipStream_t stream) {
    const float* x    = (const float*)d_in[0];  // (8,256,64,64)
    const float* coff = (const float*)d_in[1];  // (8,18,64,64)
    const float* cwm  = (const float*)d_in[2];  // (8,9,64,64)
    const float* wgt  = (const float*)d_in[3];  // (256,256,3,3)
    const float* bias = (const float*)d_in[4];  // (256,)
    float* out = (float*)d_out;                 // (8,256,64,64)

    f16_t* xt = (f16_t*)d_ws;                   // 8*64*64*256 elems
    f16_t* Wp = xt + (size_t)8 * 64 * 64 * 256; // 36*16384 elems

    k_prep<<<576, 256, 0, stream>>>(x, wgt, xt, Wp);
    k_dcn <<<512, 512, 0, stream>>>(xt, Wp, coff, cwm, bias, out);
}

// Round 7
// 195.716 us; speedup vs baseline: 1.0038x; 1.0038x over previous
//
#include <hip/hip_runtime.h>
#include <hip/hip_bf16.h>
#include <stdint.h>

typedef _Float16 f16_t;
typedef f16_t f16x8 __attribute__((ext_vector_type(8)));
typedef f16_t f16x2 __attribute__((ext_vector_type(2)));
typedef float f32x4 __attribute__((ext_vector_type(4)));

__device__ inline f16x2 as_f16x2(int v) {
    union { int i; f16x2 h; } u; u.i = v; return u.h;
}

// CK-style lgkm-only barrier: LDS producer/consumer sync WITHOUT draining
// in-flight global loads (prefetches survive across iterations).
#define LGKM_BARRIER() asm volatile("s_waitcnt lgkmcnt(0)\n\ts_barrier" ::: "memory")

// ---------------------------------------------------------------------------
// Kernel 1 (merged prep):
//  blocks 0..511  : transpose+cast x(B,C,H,W) f32 -> xt(B,H,W,C) f16.
//  blocks 512..575: pack weight (O,C,3,3) f32 -> Wp f16 A-fragment layout
//    Wp[((kb2*2+s)*256 + o)*32 + quad*8 + e], c = cp*64 + s*32 + quad*8 + e.
// ---------------------------------------------------------------------------
__global__ __launch_bounds__(256) void k_prep(const float* __restrict__ x,
                                              const float* __restrict__ w,
                                              f16_t* __restrict__ xt,
                                              f16_t* __restrict__ Wp) {
    __shared__ __align__(16) char smem[36864];
    const int t = threadIdx.x;
    if (blockIdx.x < 512) {
        f16_t* tT = (f16_t*)smem;                 // 64 x 256, swizzled, 32 KB
        const int b = blockIdx.x >> 6;
        const int y = blockIdx.x & 63;
        const float* src = x + ((size_t)(b * 256) * 64 + y) * 64;
        const int x4 = (t & 15) * 4;
        const int cs = t >> 4;
#pragma unroll
        for (int cc = 0; cc < 256; cc += 16) {
            const int c = cc + cs;
            float4 v = *(const float4*)(src + (size_t)c * 4096 + x4);
            const int chunk = c >> 3, e = c & 7;
#pragma unroll
            for (int j = 0; j < 4; ++j) {
                const int xx = x4 + j;
                const float f = (j == 0) ? v.x : (j == 1) ? v.y : (j == 2) ? v.z : v.w;
                tT[xx * 256 + ((chunk ^ (xx & 31)) << 3) + e] = (f16_t)f;
            }
        }
        __syncthreads();
        f16_t* dst = xt + ((size_t)(b * 64 + y) * 64) * 256;
#pragma unroll
        for (int i = 0; i < 8; ++i) {
            const int s = t + 256 * i;
            const int xx = s >> 5, cg = s & 31;
            *(f16x8*)(dst + xx * 256 + cg * 8) =
                *(const f16x8*)(tT + xx * 256 + ((cg ^ (xx & 31)) << 3));
        }
    } else {
        float* lw = (float*)smem;                 // 4*2304 f32 = 36864 B
        const int o0 = (blockIdx.x - 512) * 4;
        const float4* src = (const float4*)(w + (size_t)o0 * 2304);
#pragma unroll
        for (int i = 0; i < 9; ++i)
            ((float4*)lw)[t + 256 * i] = src[t + 256 * i];
        __syncthreads();
#pragma unroll
        for (int i = 0; i < 5; ++i) {
            const int u = t + 256 * i;            // 0..1151
            if (u < 1152) {
                const int o = u / 288, r = u - o * 288;
                const int kb2 = r >> 3, rr = r & 7;
                const int s = rr >> 2, qq = rr & 3;
                const int kk = kb2 >> 2, cp = kb2 & 3;
                f16x8 v;
#pragma unroll
                for (int e = 0; e < 8; ++e) {
                    const int c = cp * 64 + s * 32 + qq * 8 + e;
                    v[e] = (f16_t)lw[o * 2304 + c * 9 + kk];
                }
                *(f16x8*)(Wp + ((size_t)(kb2 * 2 + s) * 256 + o0 + o) * 32 + qq * 8) = v;
            }
        }
    }
}

// ---------------------------------------------------------------------------
// Kernel 2: fused deformable-sample + GEMM, f16, depth-2 gather pipeline.
// Explicit even/odd bodies (no dynamic register-array indexing -> no spill);
// waves_per_eu(4,4) budgets 128 VGPRs (grid is 2 blocks/CU anyway).
// Per iter: gather(it+2) | loadA(it+1) | MFMA(it) | combine(it+1) | lgkm-bar.
// ---------------------------------------------------------------------------
__global__ __launch_bounds__(512)
__attribute__((amdgpu_waves_per_eu(4, 4)))
void k_dcn(
    const f16_t* __restrict__ xt, const f16_t* __restrict__ Wp,
    const float* __restrict__ coff, const float* __restrict__ cwm,
    const float* __restrict__ bias, float* __restrict__ out) {

    __shared__ __align__(16) f16_t sS[2][64 * 64];   // 2 x 8 KB
    __shared__ __align__(16) int2 sT[9 * 64 * 4];    // [kk][px][corner] 18 KB

    const int blk = blockIdx.x;
    const int b  = blk & 7;
    const int h  = blk >> 3;
    const int t = threadIdx.x;
    const int wv = t >> 6;
    const int lane = t & 63;

    const int p = t >> 3;          // pixel (8 threads/pixel)
    const int q = t & 7;           // 8-channel slice

    const int fr = lane & 15;
    const int quad = lane >> 4;
    const int swz = fr & 7;

    // ---- precompute corner table for all 9 taps ----
    for (int u = t; u < 576; u += 512) {
        const int kk = u >> 6, wpx = u & 63;
        float oy = coff[((size_t)(b * 18 + kk * 2 + 0) * 64 + h) * 64 + wpx];
        float ox = coff[((size_t)(b * 18 + kk * 2 + 1) * 64 + h) * 64 + wpx];
        float m  = cwm [((size_t)(b * 9 + kk) * 64 + h) * 64 + wpx];
        float py = (float)(h - 1 + (kk / 3)) + oy;
        float px = (float)(wpx - 1 + (kk % 3)) + ox;
        float fy = floorf(py), fx = floorf(px);
        int y0 = (int)fy, x0 = (int)fx;
        int y1 = y0 + 1,  x1 = x0 + 1;
        float wy1 = py - fy, wx1 = px - fx;
        float wy0 = 1.0f - wy1, wx0 = 1.0f - wx1;
        bool vy0 = (y0 >= 0) && (y0 < 64), vy1 = (y1 >= 0) && (y1 < 64);
        bool vx0 = (x0 >= 0) && (x0 < 64), vx1 = (x1 >= 0) && (x1 < 64);
        int yc0 = min(max(y0, 0), 63), yc1 = min(max(y1, 0), 63);
        int xc0 = min(max(x0, 0), 63), xc1 = min(max(x1, 0), 63);
        const int base = b * 4096;
        float cw[4];
        int   ca[4];
        cw[0] = (vy0 && vx0) ? wy0 * wx0 * m : 0.0f;
        cw[1] = (vy0 && vx1) ? wy0 * wx1 * m : 0.0f;
        cw[2] = (vy1 && vx0) ? wy1 * wx0 * m : 0.0f;
        cw[3] = (vy1 && vx1) ? wy1 * wx1 * m : 0.0f;
        ca[0] = (base + yc0 * 64 + xc0) * 512;   // byte offsets (f16)
        ca[1] = (base + yc0 * 64 + xc1) * 512;
        ca[2] = (base + yc1 * 64 + xc0) * 512;
        ca[3] = (base + yc1 * 64 + xc1) * 512;
#pragma unroll
        for (int c = 0; c < 4; ++c) {
            union { unsigned short us; f16_t hh; } cv;
            cv.hh = (f16_t)cw[c];
            int wp = (int)cv.us | ((int)cv.us << 16);
            sT[(kk * 64 + wpx) * 4 + c] = make_int2(ca[c], wp);
        }
    }
    __syncthreads();

    // A-frag global base (elems): + it*16384 + s*8192 + mt*512
    const f16_t* wA = Wp + (wv * 32 + fr) * 32 + quad * 8;
    f16_t* const swb0 = &sS[0][p * 64 + ((q ^ (p & 7)) * 8)];
    const int qb = q * 16;                       // byte offset of ch slice

    f32x4 acc[2][4] = {};
    // named register sets (NO dynamic indexing anywhere)
    f16x8 aE0, aE1, aE2, aE3;    // A-frags even iters: [mt0 s0, mt0 s1, mt1 s0, mt1 s1]
    f16x8 aO0, aO1, aO2, aO3;    // A-frags odd iters
    f16x8 gE0, gE1, gE2, gE3;    // gathers even iters
    f16x8 gO0, gO1, gO2, gO3;    // gathers odd iters
    int   wE0, wE1, wE2, wE3;    // packed corner weights even
    int   wO0, wO1, wO2, wO3;    // packed corner weights odd

#define GATHER(it, g0, g1, g2, g3, pw0, pw1, pw2, pw3)                         \
    {                                                                          \
        const int kk_ = (it) >> 2, cp_ = (it) & 3;                             \
        const int4* tp_ = (const int4*)&sT[(kk_ * 64 + p) * 4];                \
        int4 t0_ = tp_[0], t1_ = tp_[1];                                       \
        const int cb_ = cp_ * 128 + qb;                                        \
        const char* xb_ = (const char*)xt;                                     \
        g0 = *(const f16x8*)(xb_ + (t0_.x + cb_));                             \
        g1 = *(const f16x8*)(xb_ + (t0_.z + cb_));                             \
        g2 = *(const f16x8*)(xb_ + (t1_.x + cb_));                             \
        g3 = *(const f16x8*)(xb_ + (t1_.z + cb_));                             \
        pw0 = t0_.y; pw1 = t0_.w; pw2 = t1_.y; pw3 = t1_.w;                    \
    }

#define LOADA(it, a0, a1, a2, a3)                                              \
    {                                                                          \
        const f16_t* wn_ = wA + (size_t)(it) * 16384;                          \
        a0 = *(const f16x8*)(wn_);                                             \
        a1 = *(const f16x8*)(wn_ + 8192);                                      \
        a2 = *(const f16x8*)(wn_ + 512);                                       \
        a3 = *(const f16x8*)(wn_ + 8192 + 512);                                \
    }

#define COMBINE(par, g0, g1, g2, g3, pw0, pw1, pw2, pw3)                       \
    {                                                                          \
        f16x2 cw0_ = as_f16x2(pw0), cw1_ = as_f16x2(pw1);                      \
        f16x2 cw2_ = as_f16x2(pw2), cw3_ = as_f16x2(pw3);                      \
        const f16x2* p0_ = (const f16x2*)&g0;                                  \
        const f16x2* p1_ = (const f16x2*)&g1;                                  \
        const f16x2* p2_ = (const f16x2*)&g2;                                  \
        const f16x2* p3_ = (const f16x2*)&g3;                                  \
        f16x8 ov_; f16x2* op_ = (f16x2*)&ov_;                                  \
        _Pragma("unroll")                                                      \
        for (int j = 0; j < 4; ++j)                                            \
            op_[j] = p0_[j] * cw0_ + p1_[j] * cw1_ + p2_[j] * cw2_ + p3_[j] * cw3_; \
        *(f16x8*)(swb0 + (par) * 4096) = ov_;                                  \
    }

#define DO_MFMA(par, a0, a1, a2, a3)                                           \
    {                                                                          \
        const f16_t* sb_ = &sS[par][0];                                        \
        {                                                                      \
            const int co_ = ((0 * 4 + quad) ^ swz) * 8;                        \
            f16x8 b0_ = *(const f16x8*)(sb_ + (0 * 16 + fr) * 64 + co_);       \
            f16x8 b1_ = *(const f16x8*)(sb_ + (1 * 16 + fr) * 64 + co_);       \
            f16x8 b2_ = *(const f16x8*)(sb_ + (2 * 16 + fr) * 64 + co_);       \
            f16x8 b3_ = *(const f16x8*)(sb_ + (3 * 16 + fr) * 64 + co_);       \
            acc[0][0] = __builtin_amdgcn_mfma_f32_16x16x32_f16(a0, b0_, acc[0][0], 0, 0, 0); \
            acc[0][1] = __builtin_amdgcn_mfma_f32_16x16x32_f16(a0, b1_, acc[0][1], 0, 0, 0); \
            acc[0][2] = __builtin_amdgcn_mfma_f32_16x16x32_f16(a0, b2_, acc[0][2], 0, 0, 0); \
            acc[0][3] = __builtin_amdgcn_mfma_f32_16x16x32_f16(a0, b3_, acc[0][3], 0, 0, 0); \
            acc[1][0] = __builtin_amdgcn_mfma_f32_16x16x32_f16(a2, b0_, acc[1][0], 0, 0, 0); \
            acc[1][1] = __builtin_amdgcn_mfma_f32_16x16x32_f16(a2, b1_, acc[1][1], 0, 0, 0); \
            acc[1][2] = __builtin_amdgcn_mfma_f32_16x16x32_f16(a2, b2_, acc[1][2], 0, 0, 0); \
            acc[1][3] = __builtin_amdgcn_mfma_f32_16x16x32_f16(a2, b3_, acc[1][3], 0, 0, 0); \
        }                                                                      \
        {                                                                      \
            const int co_ = ((1 * 4 + quad) ^ swz) * 8;                        \
            f16x8 b0_ = *(const f16x8*)(sb_ + (0 * 16 + fr) * 64 + co_);       \
            f16x8 b1_ = *(const f16x8*)(sb_ + (1 * 16 + fr) * 64 + co_);       \
            f16x8 b2_ = *(const f16x8*)(sb_ + (2 * 16 + fr) * 64 + co_);       \
            f16x8 b3_ = *(const f16x8*)(sb_ + (3 * 16 + fr) * 64 + co_);       \
            acc[0][0] = __builtin_amdgcn_mfma_f32_16x16x32_f16(a1, b0_, acc[0][0], 0, 0, 0); \
            acc[0][1] = __builtin_amdgcn_mfma_f32_16x16x32_f16(a1, b1_, acc[0][1], 0, 0, 0); \
            acc[0][2] = __builtin_amdgcn_mfma_f32_16x16x32_f16(a1, b2_, acc[0][2], 0, 0, 0); \
            acc[0][3] = __builtin_amdgcn_mfma_f32_16x16x32_f16(a1, b3_, acc[0][3], 0, 0, 0); \
            acc[1][0] = __builtin_amdgcn_mfma_f32_16x16x32_f16(a3, b0_, acc[1][0], 0, 0, 0); \
            acc[1][1] = __builtin_amdgcn_mfma_f32_16x16x32_f16(a3, b1_, acc[1][1], 0, 0, 0); \
            acc[1][2] = __builtin_amdgcn_mfma_f32_16x16x32_f16(a3, b2_, acc[1][2], 0, 0, 0); \
            acc[1][3] = __builtin_amdgcn_mfma_f32_16x16x32_f16(a3, b3_, acc[1][3], 0, 0, 0); \
        }                                                                      \
    }

    // ---- prologue: fill depth-2 pipeline ----
    GATHER(0, gE0, gE1, gE2, gE3, wE0, wE1, wE2, wE3);
    GATHER(1, gO0, gO1, gO2, gO3, wO0, wO1, wO2, wO3);
    LOADA(0, aE0, aE1, aE2, aE3);
    COMBINE(0, gE0, gE1, gE2, gE3, wE0, wE1, wE2, wE3);
    LGKM_BARRIER();             // sS[0] visible; vmem NOT drained

    // ---- main loop: step 2, explicit even/odd bodies ----
#pragma unroll 1
    for (int it = 0; it < 36; it += 2) {
        // EVEN body (iter it): A=aE, B=sS[0]
        if (it + 2 < 36) GATHER(it + 2, gE0, gE1, gE2, gE3, wE0, wE1, wE2, wE3);
        LOADA(it + 1, aO0, aO1, aO2, aO3);
        DO_MFMA(0, aE0, aE1, aE2, aE3);
        COMBINE(1, gO0, gO1, gO2, gO3, wO0, wO1, wO2, wO3);
        LGKM_BARRIER();
        // ODD body (iter it+1): A=aO, B=sS[1]
        if (it + 3 < 36) GATHER(it + 3, gO0, gO1, gO2, gO3, wO0, wO1, wO2, wO3);
        if (it + 2 < 36) LOADA(it + 2, aE0, aE1, aE2, aE3);
        DO_MFMA(1, aO0, aO1, aO2, aO3);
        if (it + 2 < 36) COMBINE(0, gE0, gE1, gE2, gE3, wE0, wE1, wE2, wE3);
        LGKM_BARRIER();
    }

    // ---- epilogue: D layout col=lane&15 (px), row=(lane>>4)*4+r (O) ----
    const int rowq = quad * 4;
#pragma unroll
    for (int mt = 0; mt < 2; ++mt) {
#pragma unroll
        for (int r = 0; r < 4; ++r) {
            const int og = wv * 32 + mt * 16 + rowq + r;
            const float bs = bias[og];
            float* opn = out + ((size_t)(b * 256 + og) * 64 + h) * 64;
#pragma unroll
            for (int nt = 0; nt < 4; ++nt) {
                opn[nt * 16 + fr] = acc[mt][nt][r] + bs;
            }
        }
    }
#undef GATHER
#undef LOADA
#undef COMBINE
#undef DO_MFMA
}

// ---------------------------------------------------------------------------
extern "C" void kernel_launch(void* const* d_in, const int* in_sizes, int n_in,
                              void* d_out, int out_size, void* d_ws, size_t ws_size,
                              hipStream_t stream) {
    const float* x    = (const float*)d_in[0];  // (8,256,64,64)
    const float* coff = (const float*)d_in[1];  // (8,18,64,64)
    const float* cwm  = (const float*)d_in[2];  // (8,9,64,64)
    const float* wgt  = (const float*)d_in[3];  // (256,256,3,3)
    const float* bias = (const float*)d_in[4];  // (256,)
    float* out = (float*)d_out;                 // (8,256,64,64)

    f16_t* xt = (f16_t*)d_ws;                   // 8*64*64*256 elems
    f16_t* Wp = xt + (size_t)8 * 64 * 64 * 256; // 36*16384 elems

    k_prep<<<576, 256, 0, stream>>>(x, wgt, xt, Wp);
    k_dcn <<<512, 512, 0, stream>>>(xt, Wp, coff, cwm, bias, out);
}

// Round 8
// 149.059 us; speedup vs baseline: 1.3179x; 1.3130x over previous
//
#include <hip/hip_runtime.h>
#include <hip/hip_bf16.h>
#include <stdint.h>

typedef _Float16 f16_t;
typedef f16_t f16x8 __attribute__((ext_vector_type(8)));
typedef float f32x4 __attribute__((ext_vector_type(4)));

// lgkm-only barrier via proper intrinsics (no asm memory clobber -> no
// forced stack materialization of live registers). 0xC07F = vmcnt(63)
// expcnt(7) lgkmcnt(0): waits LDS ops only; global prefetches stay in flight.
__device__ inline void lgkm_barrier() {
    __builtin_amdgcn_s_waitcnt(0xC07F);
    __builtin_amdgcn_s_barrier();
}

// ---------------------------------------------------------------------------
// Kernel 1 (merged prep):
//  blocks 0..511  : transpose+cast x(B,C,H,W) f32 -> xt(B,H,W,C) f16.
//  blocks 512..575: pack weight (O,C,3,3) f32 -> Wp f16 A-fragment layout
//    Wp[((kb2*2+s)*256 + o)*32 + quad*8 + e], c = cp*64 + s*32 + quad*8 + e.
// ---------------------------------------------------------------------------
__global__ __launch_bounds__(256) void k_prep(const float* __restrict__ x,
                                              const float* __restrict__ w,
                                              f16_t* __restrict__ xt,
                                              f16_t* __restrict__ Wp) {
    __shared__ __align__(16) char smem[36864];
    const int t = threadIdx.x;
    if (blockIdx.x < 512) {
        f16_t* tT = (f16_t*)smem;                 // 64 x 256, swizzled, 32 KB
        const int b = blockIdx.x >> 6;
        const int y = blockIdx.x & 63;
        const float* src = x + ((size_t)(b * 256) * 64 + y) * 64;
        const int x4 = (t & 15) * 4;
        const int cs = t >> 4;
#pragma unroll
        for (int cc = 0; cc < 256; cc += 16) {
            const int c = cc + cs;
            float4 v = *(const float4*)(src + (size_t)c * 4096 + x4);
            const int chunk = c >> 3, e = c & 7;
#pragma unroll
            for (int j = 0; j < 4; ++j) {
                const int xx = x4 + j;
                const float f = (j == 0) ? v.x : (j == 1) ? v.y : (j == 2) ? v.z : v.w;
                tT[xx * 256 + ((chunk ^ (xx & 31)) << 3) + e] = (f16_t)f;
            }
        }
        __syncthreads();
        f16_t* dst = xt + ((size_t)(b * 64 + y) * 64) * 256;
#pragma unroll
        for (int i = 0; i < 8; ++i) {
            const int s = t + 256 * i;
            const int xx = s >> 5, cg = s & 31;
            *(f16x8*)(dst + xx * 256 + cg * 8) =
                *(const f16x8*)(tT + xx * 256 + ((cg ^ (xx & 31)) << 3));
        }
    } else {
        float* lw = (float*)smem;                 // 4*2304 f32 = 36864 B
        const int o0 = (blockIdx.x - 512) * 4;
        const float4* src = (const float4*)(w + (size_t)o0 * 2304);
#pragma unroll
        for (int i = 0; i < 9; ++i)
            ((float4*)lw)[t + 256 * i] = src[t + 256 * i];
        __syncthreads();
#pragma unroll
        for (int i = 0; i < 5; ++i) {
            const int u = t + 256 * i;            // 0..1151
            if (u < 1152) {
                const int o = u / 288, r = u - o * 288;
                const int kb2 = r >> 3, rr = r & 7;
                const int s = rr >> 2, qq = rr & 3;
                const int kk = kb2 >> 2, cp = kb2 & 3;
                f16x8 v;
#pragma unroll
                for (int e = 0; e < 8; ++e) {
                    const int c = cp * 64 + s * 32 + qq * 8 + e;
                    v[e] = (f16_t)lw[o * 2304 + c * 9 + kk];
                }
                *(f16x8*)(Wp + ((size_t)(kb2 * 2 + s) * 256 + o0 + o) * 32 + qq * 8) = v;
            }
        }
    }
}

// ---------------------------------------------------------------------------
// Kernel 2: fused deformable-sample + GEMM, f16, depth-1 pipeline with
// lgkm-only barriers (A-prefetch survives the barrier; no vmcnt(0) drain).
// Grid 512: b = blk&7 (XCD pin), h = blk>>3; 512 threads, 2 blocks/CU.
// Per iter: gather(it+1) | loadA(it+1) | MFMA(it) | combine(it+1) | lgkm-bar.
// ---------------------------------------------------------------------------
__global__ __launch_bounds__(512, 4) void k_dcn(
    const f16_t* __restrict__ xt, const f16_t* __restrict__ Wp,
    const float* __restrict__ coff, const float* __restrict__ cwm,
    const float* __restrict__ bias, float* __restrict__ out) {

    __shared__ __align__(16) f16_t sS[2][64 * 64];   // 2 x 8 KB
    __shared__ __align__(16) int2 sT[9 * 64 * 4];    // [kk][px][corner] 18 KB

    const int blk = blockIdx.x;
    const int b  = blk & 7;
    const int h  = blk >> 3;
    const int t = threadIdx.x;
    const int wv = t >> 6;
    const int lane = t & 63;

    const int p = t >> 3;          // pixel (8 threads/pixel)
    const int q = t & 7;           // 8-channel slice

    const int fr = lane & 15;
    const int quad = lane >> 4;
    const int swz = fr & 7;

    // ---- precompute corner table for all 9 taps ----
    for (int u = t; u < 576; u += 512) {
        const int kk = u >> 6, wpx = u & 63;
        float oy = coff[((size_t)(b * 18 + kk * 2 + 0) * 64 + h) * 64 + wpx];
        float ox = coff[((size_t)(b * 18 + kk * 2 + 1) * 64 + h) * 64 + wpx];
        float m  = cwm [((size_t)(b * 9 + kk) * 64 + h) * 64 + wpx];
        float py = (float)(h - 1 + (kk / 3)) + oy;
        float px = (float)(wpx - 1 + (kk % 3)) + ox;
        float fy = floorf(py), fx = floorf(px);
        int y0 = (int)fy, x0 = (int)fx;
        int y1 = y0 + 1,  x1 = x0 + 1;
        float wy1 = py - fy, wx1 = px - fx;
        float wy0 = 1.0f - wy1, wx0 = 1.0f - wx1;
        bool vy0 = (y0 >= 0) && (y0 < 64), vy1 = (y1 >= 0) && (y1 < 64);
        bool vx0 = (x0 >= 0) && (x0 < 64), vx1 = (x1 >= 0) && (x1 < 64);
        int yc0 = min(max(y0, 0), 63), yc1 = min(max(y1, 0), 63);
        int xc0 = min(max(x0, 0), 63), xc1 = min(max(x1, 0), 63);
        const int base = b * 4096;
        float cw[4];
        int   ca[4];
        cw[0] = (vy0 && vx0) ? wy0 * wx0 * m : 0.0f;
        cw[1] = (vy0 && vx1) ? wy0 * wx1 * m : 0.0f;
        cw[2] = (vy1 && vx0) ? wy1 * wx0 * m : 0.0f;
        cw[3] = (vy1 && vx1) ? wy1 * wx1 * m : 0.0f;
        ca[0] = (base + yc0 * 64 + xc0) * 512;   // byte offsets (f16)
        ca[1] = (base + yc0 * 64 + xc1) * 512;
        ca[2] = (base + yc1 * 64 + xc0) * 512;
        ca[3] = (base + yc1 * 64 + xc1) * 512;
#pragma unroll
        for (int c = 0; c < 4; ++c) {
            unsigned short ws = __builtin_bit_cast(unsigned short, (f16_t)cw[c]);
            sT[(kk * 64 + wpx) * 4 + c] = make_int2(ca[c], (int)ws);
        }
    }
    __syncthreads();

    // A-frag global base (elems): + it*16384 + s*8192 + mt*512
    const f16_t* wA = Wp + (wv * 32 + fr) * 32 + quad * 8;
    f16_t* const swb0 = &sS[0][p * 64 + ((q ^ (p & 7)) * 8)];
    const int qb = q * 16;                       // byte offset of ch slice

    f32x4 acc[2][4] = {};
    f16x8 aC[2][2], aN[2][2];

    auto loadA = [&](int it, f16x8 (&a)[2][2]) {
        const f16_t* wn = wA + (size_t)it * 16384;
        a[0][0] = *(const f16x8*)(wn);
        a[0][1] = *(const f16x8*)(wn + 8192);
        a[1][0] = *(const f16x8*)(wn + 512);
        a[1][1] = *(const f16x8*)(wn + 8192 + 512);
    };

    auto do_mfma = [&](int cur) {
        const f16_t* sb = &sS[cur][0];
#pragma unroll
        for (int s = 0; s < 2; ++s) {
            const int coffe = ((s * 4 + quad) ^ swz) * 8;
            f16x8 bb[4];
#pragma unroll
            for (int nt = 0; nt < 4; ++nt)
                bb[nt] = *(const f16x8*)(sb + (nt * 16 + fr) * 64 + coffe);
#pragma unroll
            for (int mt = 0; mt < 2; ++mt)
#pragma unroll
                for (int nt = 0; nt < 4; ++nt)
                    acc[mt][nt] = __builtin_amdgcn_mfma_f32_16x16x32_f16(
                        aC[mt][s], bb[nt], acc[mt][nt], 0, 0, 0);
        }
    };

    // sample iter `it` into buffer `buf` — NO address-taking, NO unions:
    // whole-vector f16 math (compiles to v_pk_*_f16).
    auto sample_into = [&](int it, int buf) {
        const int kk = it >> 2, cp = it & 3;
        const int4* tp = (const int4*)&sT[(kk * 64 + p) * 4];
        int4 t0 = tp[0], t1 = tp[1];             // 2x ds_read_b128
        const int cb = cp * 128 + qb;
        const char* xb = (const char*)xt;
        f16x8 g0 = *(const f16x8*)(xb + (t0.x + cb));
        f16x8 g1 = *(const f16x8*)(xb + (t0.z + cb));
        f16x8 g2 = *(const f16x8*)(xb + (t1.x + cb));
        f16x8 g3 = *(const f16x8*)(xb + (t1.z + cb));
        f16_t w0 = __builtin_bit_cast(f16_t, (unsigned short)t0.y);
        f16_t w1 = __builtin_bit_cast(f16_t, (unsigned short)t0.w);
        f16_t w2 = __builtin_bit_cast(f16_t, (unsigned short)t1.y);
        f16_t w3 = __builtin_bit_cast(f16_t, (unsigned short)t1.w);
        f16x8 w0v = {w0, w0, w0, w0, w0, w0, w0, w0};
        f16x8 w1v = {w1, w1, w1, w1, w1, w1, w1, w1};
        f16x8 w2v = {w2, w2, w2, w2, w2, w2, w2, w2};
        f16x8 w3v = {w3, w3, w3, w3, w3, w3, w3, w3};
        f16x8 ov = g0 * w0v + g1 * w1v + g2 * w2v + g3 * w3v;
        *(f16x8*)(swb0 + buf * 4096) = ov;
    };

    // ---- prologue ----
    sample_into(0, 0);
    loadA(0, aC);
    lgkm_barrier();             // sS[0] visible; global loads NOT drained

    // ---- main loop: one lgkm-only barrier per iter ----
#pragma unroll 2
    for (int it = 0; it < 36; ++it) {
        const int cur = it & 1;
        if (it < 35) {
            sample_into(it + 1, 1 - cur);   // gathers + combine for it+1
            loadA(it + 1, aN);              // A-prefetch (survives barrier)
            do_mfma(cur);
#pragma unroll
            for (int mt = 0; mt < 2; ++mt)
#pragma unroll
                for (int s = 0; s < 2; ++s) aC[mt][s] = aN[mt][s];
        } else {
            do_mfma(cur);
        }
        lgkm_barrier();
    }

    // ---- epilogue: D layout col=lane&15 (px), row=(lane>>4)*4+r (O) ----
    const int rowq = quad * 4;
#pragma unroll
    for (int mt = 0; mt < 2; ++mt) {
#pragma unroll
        for (int r = 0; r < 4; ++r) {
            const int og = wv * 32 + mt * 16 + rowq + r;
            const float bs = bias[og];
            float* opn = out + ((size_t)(b * 256 + og) * 64 + h) * 64;
#pragma unroll
            for (int nt = 0; nt < 4; ++nt) {
                opn[nt * 16 + fr] = acc[mt][nt][r] + bs;
            }
        }
    }
}

// ---------------------------------------------------------------------------
extern "C" void kernel_launch(void* const* d_in, const int* in_sizes, int n_in,
                              void* d_out, int out_size, void* d_ws, size_t ws_size,
                              hipStream_t stream) {
    const float* x    = (const float*)d_in[0];  // (8,256,64,64)
    const float* coff = (const float*)d_in[1];  // (8,18,64,64)
    const float* cwm  = (const float*)d_in[2];  // (8,9,64,64)
    const float* wgt  = (const float*)d_in[3];  // (256,256,3,3)
    const float* bias = (const float*)d_in[4];  // (256,)
    float* out = (float*)d_out;                 // (8,256,64,64)

    f16_t* xt = (f16_t*)d_ws;                   // 8*64*64*256 elems
    f16_t* Wp = xt + (size_t)8 * 64 * 64 * 256; // 36*16384 elems

    k_prep<<<576, 256, 0, stream>>>(x, wgt, xt, Wp);
    k_dcn <<<512, 512, 0, stream>>>(xt, Wp, coff, cwm, bias, out);
}